// Round 6
// baseline (296.180 us; speedup 1.0000x reference)
//
#include <hip/hip_runtime.h>

typedef unsigned short u16;
typedef __bf16 bf16x8 __attribute__((ext_vector_type(8)));
typedef float f32x4 __attribute__((ext_vector_type(4)));
typedef float f32x16 __attribute__((ext_vector_type(16)));

#define LOG2E 1.44269504088896f

__device__ inline u16 f2b(float f) {
    unsigned u = __float_as_uint(f);
    u += 0x7fff + ((u >> 16) & 1);
    return (u16)(u >> 16);
}
__device__ inline float b2f(u16 u) { return __uint_as_float(((unsigned)u) << 16); }
__device__ inline unsigned pk2(float a, float b) {
    return (unsigned)f2b(a) | ((unsigned)f2b(b) << 16);
}
__device__ inline uint4 pack8(float4 a, float4 b) {
    return uint4{pk2(a.x, a.y), pk2(a.z, a.w), pk2(b.x, b.y), pk2(b.z, b.w)};
}
__device__ inline f32x4 mfma16(uint4 a, uint4 b, f32x4 c) {
    return __builtin_amdgcn_mfma_f32_16x16x32_bf16(
        __builtin_bit_cast(bf16x8, a), __builtin_bit_cast(bf16x8, b), c, 0, 0, 0);
}
__device__ inline f32x16 mfma32(uint4 a, uint4 b, f32x16 c) {
    return __builtin_amdgcn_mfma_f32_32x32x16_bf16(
        __builtin_bit_cast(bf16x8, a), __builtin_bit_cast(bf16x8, b), c, 0, 0, 0);
}
// async global->LDS: per-lane global src, wave-uniform LDS base (+lane*16 by HW)
__device__ inline void ld16(const u16* g, u16* l) {
    __builtin_amdgcn_global_load_lds(
        (const __attribute__((address_space(1))) unsigned int*)g,
        (__attribute__((address_space(3))) unsigned int*)l, 16, 0, 0);
}

// ---------------------------------------------------------------------------
// Weight prep (f32 -> bf16):
//   WkT[e][d] = Wqk[1][d][e],  WvT[e][d] = Wv[d][e],  Wqb[c][d] = Wqk[0][c][d]
// ---------------------------------------------------------------------------
__global__ __launch_bounds__(256) void prep_w(const float* __restrict__ Wqk,
                                              const float* __restrict__ Wv,
                                              u16* __restrict__ WkT,
                                              u16* __restrict__ WvT,
                                              u16* __restrict__ Wqb) {
    int idx = blockIdx.x * 256 + threadIdx.x;   // 0 .. 196607
    int which = idx >> 16;
    int i = (idx >> 8) & 255;
    int j = idx & 255;
    if (which == 0)
        WkT[i * 256 + j] = f2b(Wqk[65536 + j * 256 + i]);
    else if (which == 1)
        WvT[i * 256 + j] = f2b(Wv[j * 256 + i]);
    else
        Wqb[i * 256 + j] = f2b(Wqk[i * 256 + j]);
}

// ===========================================================================
// Fused K+V projection + Xb side-write.  Block = 64 X-rows x (256 K-cols +
// 256 V-cols).  4 waves: wave = (rh = w&1: 32 rows) x (chalf = w>>1: 128 cols
// of BOTH K and V) -> 8 x f32x16 acc.  B staged via global_load_lds per
// 32-k step (m97 2-barrier loop).  A (f32) reg-prefetched + packed.
// LDS chunk layout [s(16k)][h(8k)][row][8elem] -> conflict-free b128 frags.
// ===========================================================================
__global__ __launch_bounds__(256, 2) void gemm_kvx(const float* __restrict__ A,
                                                   const u16* __restrict__ BtK,
                                                   const u16* __restrict__ BtV,
                                                   const float* __restrict__ biasK,
                                                   const float* __restrict__ biasV,
                                                   u16* __restrict__ KT,
                                                   u16* __restrict__ VT,
                                                   u16* __restrict__ Xb) {
    __shared__ __align__(16) u16 lds[18432];  // As[0,2048) Bs[2048,18432); Ct aliases
    u16* As = lds;          // [s][h][64 r][8] : s*1024 + h*512 + r*8
    u16* Bs = lds + 2048;   // [s][h][rb*256+r][8] : s*8192 + h*4096 + rb*2048 + r*8

    const int t = threadIdx.x;
    const int r0 = blockIdx.x * 64;
    const int w = t >> 6, lane = t & 63, l31 = lane & 31, h = lane >> 5;
    const int rh = w & 1, chalf = w >> 1;

    f32x16 acc[8];          // [0..3] = K col-tiles, [4..7] = V col-tiles
#pragma unroll
    for (int c = 0; c < 8; ++c) acc[c] = (f32x16)0.f;

    const int ar = t >> 2, asg = t & 3;    // A staging: row, k-chunk
    const float* Arow = A + (long)(r0 + ar) * 256 + asg * 8;
    u16* AsW = As + (asg >> 1) * 1024 + (asg & 1) * 512 + ar * 8;
    u16* XbW = Xb ? Xb + (long)(r0 + ar) * 256 + asg * 8 : (u16*)0;

    float4 a0 = ((const float4*)Arow)[0];
    float4 a1 = ((const float4*)Arow)[1];

    for (int k0 = 0; k0 < 256; k0 += 32) {
        // B: 8 sweeps, j = (s, hh, rb); thread t -> weight row t
#pragma unroll
        for (int j = 0; j < 8; ++j) {
            const int s = j >> 2, hh = (j >> 1) & 1, rb = j & 1;
            const u16* src = rb ? BtV : BtK;
            ld16(src + t * 256 + k0 + s * 16 + hh * 8,
                 Bs + s * 8192 + hh * 4096 + rb * 2048 + w * 512);
        }
        uint4 ap = pack8(a0, a1);
        *(uint4*)AsW = ap;
        if (XbW) *(uint4*)(XbW + k0) = ap;
        if (k0 + 32 < 256) {
            a0 = ((const float4*)(Arow + k0 + 32))[0];
            a1 = ((const float4*)(Arow + k0 + 32))[1];
        }
        __syncthreads();
#pragma unroll
        for (int s = 0; s < 2; ++s) {
            uint4 af = *(const uint4*)(As + s * 1024 + h * 512 + (rh * 32 + l31) * 8);
#pragma unroll
            for (int pass = 0; pass < 2; ++pass)
#pragma unroll
                for (int ctl = 0; ctl < 4; ++ctl) {
                    uint4 bf = *(const uint4*)(Bs + s * 8192 + h * 4096 +
                                               (pass * 256 + chalf * 128 + ctl * 32 + l31) * 8);
                    acc[pass * 4 + ctl] = mfma32(af, bf, acc[pass * 4 + ctl]);
                }
        }
        __syncthreads();
    }

    // epilogue: bias + transpose through LDS Ct[256 d][68 n] (34 KB), K then V
    const int bb = r0 >> 13, n0 = r0 & 8191;
    u16* Ct = lds;
#pragma unroll
    for (int pass = 0; pass < 2; ++pass) {
        const float* bias = pass ? biasV : biasK;
        u16* CT = pass ? VT : KT;
        __syncthreads();
#pragma unroll
        for (int ctl = 0; ctl < 4; ++ctl) {
            const int d = chalf * 128 + ctl * 32 + l31;
            const float bv = bias[d];
            const f32x16 a = acc[pass * 4 + ctl];
#pragma unroll
            for (int rg = 0; rg < 4; ++rg) {
                ushort4 pk4;
                pk4.x = f2b(a[rg * 4 + 0] + bv);
                pk4.y = f2b(a[rg * 4 + 1] + bv);
                pk4.z = f2b(a[rg * 4 + 2] + bv);
                pk4.w = f2b(a[rg * 4 + 3] + bv);
                *(ushort4*)&Ct[d * 68 + rh * 32 + rg * 8 + h * 4] = pk4;
            }
        }
        __syncthreads();
        long off = ((long)bb * 256 + t) * 8192 + n0;
#pragma unroll
        for (int j = 0; j < 8; ++j)
            *(uint4*)(CT + off + j * 8) = *(const uint4*)&Ct[t * 68 + j * 8];
    }
}

// ===========================================================================
// Output GEMM: out[b][n][e] = sum_c X[n][c]*WfoldT[(b,e)][c] + outb[b][e]
// Block = 64 rows x 256 cols; A from Xb (ld16) or f32 feat (fallback).
// ===========================================================================
__global__ __launch_bounds__(256, 2) void gemm_out32(const float* __restrict__ Af,
                                                     const u16* __restrict__ Xb,
                                                     const u16* __restrict__ WfoldT,
                                                     const float* __restrict__ outb,
                                                     float* __restrict__ C) {
    __shared__ __align__(16) u16 lds[10240];  // As 2048, Bs 8192
    u16* As = lds;          // [s][h][64 r][8]
    u16* Bs = lds + 2048;   // [s][h][256 r][8] : s*4096 + h*2048 + r*8

    const int t = threadIdx.x;
    const int r0 = blockIdx.x * 64;
    const int bb = r0 >> 13;
    const int w = t >> 6, lane = t & 63, l31 = lane & 31, h = lane >> 5;
    const int rh = w & 1, chalf = w >> 1;
    const u16* Bt = WfoldT + (long)bb * 65536;

    f32x16 acc[4];
#pragma unroll
    for (int c = 0; c < 4; ++c) acc[c] = (f32x16)0.f;

    const int ar = t >> 2, asg = t & 3;
    const float* Arow = Af + (long)(r0 + ar) * 256 + asg * 8;
    u16* AsW = As + (asg >> 1) * 1024 + (asg & 1) * 512 + ar * 8;
    const u16* XbR = Xb ? Xb + (long)(r0 + lane) * 256 + w * 8 : (u16*)0;

    float4 a0, a1;
    if (!Xb) {
        a0 = ((const float4*)Arow)[0];
        a1 = ((const float4*)Arow)[1];
    }

    for (int k0 = 0; k0 < 256; k0 += 32) {
        // B: 4 sweeps, j = (s, hh); thread t -> weight row t
#pragma unroll
        for (int j = 0; j < 4; ++j) {
            const int s = j >> 1, hh = j & 1;
            ld16(Bt + t * 256 + k0 + s * 16 + hh * 8, Bs + s * 4096 + hh * 2048 + w * 512);
        }
        if (Xb) {
            ld16(XbR + k0, As + w * 512);    // wave w <-> (s,h) chunk
        } else {
            *(uint4*)AsW = pack8(a0, a1);
            if (k0 + 32 < 256) {
                a0 = ((const float4*)(Arow + k0 + 32))[0];
                a1 = ((const float4*)(Arow + k0 + 32))[1];
            }
        }
        __syncthreads();
#pragma unroll
        for (int s = 0; s < 2; ++s) {
            uint4 af = *(const uint4*)(As + s * 1024 + h * 512 + (rh * 32 + l31) * 8);
#pragma unroll
            for (int ctl = 0; ctl < 4; ++ctl) {
                uint4 bf = *(const uint4*)(Bs + s * 4096 + h * 2048 +
                                           (chalf * 128 + ctl * 32 + l31) * 8);
                acc[ctl] = mfma32(af, bf, acc[ctl]);
            }
        }
        __syncthreads();
    }

#pragma unroll
    for (int ctl = 0; ctl < 4; ++ctl) {
        const int col = chalf * 128 + ctl * 32 + l31;
        const float bv = outb[bb * 256 + col];
#pragma unroll
        for (int rg = 0; rg < 4; ++rg)
#pragma unroll
            for (int i = 0; i < 4; ++i) {
                int row = r0 + rh * 32 + rg * 8 + h * 4 + i;
                C[(long)row * 256 + col] = acc[ctl][rg * 4 + i] + bv;
            }
    }
}

// ===========================================================================
// Split-K lam GEMM (mfma32): lamP[z][(b,e)][d] = sum_{n in chunk z}
// VT[(b,e)][n] * PT[(b,d)][n].  128x128 tile, grid (16,2,16), both operands
// staged via ld16.  Wave w = rows w*32..w*32+31, all 128 cols.
// ===========================================================================
__global__ __launch_bounds__(256, 2) void gemm_splitk32(const u16* __restrict__ VT,
                                                        const u16* __restrict__ PT,
                                                        float* __restrict__ lamP,
                                                        int chunk) {
    __shared__ __align__(16) u16 lds[16384];  // As 8192, Bs 8192
    u16* As = lds;          // [s][h][128 r][8] : s*2048 + h*1024 + r*8
    u16* Bs = lds + 8192;

    const int t = threadIdx.x;
    const int r0 = blockIdx.x * 128;   // (b,e) rows
    const int c0 = blockIdx.y * 128;   // d cols
    const int z = blockIdx.z;
    const int bb = r0 >> 8;
    const long n0 = (long)z * chunk;
    const int w = t >> 6, lane = t & 63, l31 = lane & 31, h = lane >> 5;
    const int ws2 = w >> 1, wh = w & 1;   // wave <-> (s,h) for staging

    f32x16 acc[4];
#pragma unroll
    for (int c = 0; c < 4; ++c) acc[c] = (f32x16)0.f;

    const u16* Asrc = VT + (long)r0 * 8192 + n0 + ws2 * 16 + wh * 8;
    const u16* Bsrc = PT + ((long)bb * 256 + c0) * 8192 + n0 + ws2 * 16 + wh * 8;

    for (int k0 = 0; k0 < chunk; k0 += 32) {
#pragma unroll
        for (int j = 0; j < 2; ++j) {   // row halves (j*64 + lane)
            ld16(Asrc + (long)(j * 64 + lane) * 8192 + k0,
                 As + ws2 * 2048 + wh * 1024 + j * 512);
            ld16(Bsrc + (long)(j * 64 + lane) * 8192 + k0,
                 Bs + ws2 * 2048 + wh * 1024 + j * 512);
        }
        __syncthreads();
#pragma unroll
        for (int s = 0; s < 2; ++s) {
            uint4 af = *(const uint4*)(As + s * 2048 + h * 1024 + (w * 32 + l31) * 8);
#pragma unroll
            for (int ct = 0; ct < 4; ++ct) {
                uint4 bf = *(const uint4*)(Bs + s * 2048 + h * 1024 + (ct * 32 + l31) * 8);
                acc[ct] = mfma32(af, bf, acc[ct]);
            }
        }
        __syncthreads();
    }

    float* outp = lamP + (long)z * 524288;
#pragma unroll
    for (int ct = 0; ct < 4; ++ct) {
        const int col = c0 + ct * 32 + l31;
#pragma unroll
        for (int rg = 0; rg < 4; ++rg)
#pragma unroll
            for (int i = 0; i < 4; ++i) {
                int row = r0 + w * 32 + rg * 8 + h * 4 + i;
                outp[(long)row * 256 + col] = acc[ct][rg * 4 + i];
            }
    }
}

// ---------------------------------------------------------------------------
// lamT[i] = sum_s lamP[s][i]
// ---------------------------------------------------------------------------
__global__ __launch_bounds__(256) void reduce_lam(const float* __restrict__ lamP,
                                                  float* __restrict__ lamT, int S) {
    int i = blockIdx.x * 256 + threadIdx.x;  // float4 index, 131072 total
    float4 v = ((const float4*)lamP)[i];
    for (int s = 1; s < S; ++s) {
        float4 p = ((const float4*)(lamP + (long)s * 524288))[i];
        v.x += p.x; v.y += p.y; v.z += p.z; v.w += p.w;
    }
    ((float4*)lamT)[i] = v;
}

// ---------------------------------------------------------------------------
// Fold GEMM: WfoldT[(b,e)][c] = sum_d bnT[(b,e)][d] * Wqb[c][d].
// ---------------------------------------------------------------------------
__global__ __launch_bounds__(256, 4) void gemm_fold(const u16* __restrict__ Abn,
                                                    const u16* __restrict__ Wqb,
                                                    u16* __restrict__ WfoldT) {
    __shared__ __align__(16) u16 lds[4096];  // As 64x32, Bs 64x32
    u16* As = lds;
    u16* Bs = lds + 2048;

    const int t = threadIdx.x;
    const int r0 = blockIdx.x * 64;
    const int c0 = blockIdx.y * 64;
    const int w = t >> 6, lane = t & 63, l15 = lane & 15, q = lane >> 4;

    f32x4 acc[4];
#pragma unroll
    for (int c = 0; c < 4; ++c) acc[c] = f32x4{0.f, 0.f, 0.f, 0.f};

    const int br = t >> 2;
    const int bk = (t & 3) * 8;

    for (int k0 = 0; k0 < 256; k0 += 32) {
        ld16(Abn + (long)(r0 + br) * 256 + k0 + bk, As + w * 512);
        ld16(Wqb + (long)(c0 + br) * 256 + k0 + bk, Bs + w * 512);
        __syncthreads();
        uint4 af = *(const uint4*)(As + (w * 16 + l15) * 32 + q * 8);
#pragma unroll
        for (int c = 0; c < 4; ++c) {
            uint4 bf = *(const uint4*)(Bs + (c * 16 + l15) * 32 + q * 8);
            acc[c] = mfma16(af, bf, acc[c]);
        }
        __syncthreads();
    }

#pragma unroll
    for (int c = 0; c < 4; ++c) {
        int col = c0 + c * 16 + l15;
#pragma unroll
        for (int r = 0; r < 4; ++r) {
            int row = r0 + w * 16 + q * 4 + r;
            WfoldT[(long)row * 256 + col] = f2b(acc[c][r]);
        }
    }
}

// ---------------------------------------------------------------------------
// In-place softmax over each contiguous 8192-row of KT ([b*256+d][8192]).
// ---------------------------------------------------------------------------
__global__ __launch_bounds__(64) void softmax_rows(u16* __restrict__ KT) {
    const int row = blockIdx.x;
    const int lane = threadIdx.x;
    u16* p = KT + (long)row * 8192;

    uint4 buf[16];
#pragma unroll
    for (int i = 0; i < 16; ++i) buf[i] = *(const uint4*)(p + (i * 64 + lane) * 8);

    float m = -1e30f;
#pragma unroll
    for (int i = 0; i < 16; ++i) {
        const unsigned* u = (const unsigned*)&buf[i];
#pragma unroll
        for (int j = 0; j < 4; ++j) {
            m = fmaxf(m, fmaxf(b2f((u16)(u[j] & 0xffff)), b2f((u16)(u[j] >> 16))));
        }
    }
#pragma unroll
    for (int s = 32; s > 0; s >>= 1) m = fmaxf(m, __shfl_xor(m, s, 64));

    float sum = 0.f;
#pragma unroll
    for (int i = 0; i < 16; ++i) {
        const unsigned* u = (const unsigned*)&buf[i];
#pragma unroll
        for (int j = 0; j < 4; ++j) {
            sum += exp2f((b2f((u16)(u[j] & 0xffff)) - m) * LOG2E);
            sum += exp2f((b2f((u16)(u[j] >> 16)) - m) * LOG2E);
        }
    }
#pragma unroll
    for (int s = 32; s > 0; s >>= 1) sum += __shfl_xor(sum, s, 64);
    float rl = 1.0f / sum;

#pragma unroll
    for (int i = 0; i < 16; ++i) {
        unsigned* u = (unsigned*)&buf[i];
#pragma unroll
        for (int j = 0; j < 4; ++j) {
            float a = exp2f((b2f((u16)(u[j] & 0xffff)) - m) * LOG2E) * rl;
            float b = exp2f((b2f((u16)(u[j] >> 16)) - m) * LOG2E) * rl;
            u[j] = (unsigned)f2b(a) | ((unsigned)f2b(b) << 16);
        }
        *(uint4*)(p + (i * 64 + lane) * 8) = buf[i];
    }
}

// ---------------------------------------------------------------------------
// BatchNorm over lam^T[(b*256+e)][d]: stats per d over 2048 (b,e) values.
// ---------------------------------------------------------------------------
__global__ __launch_bounds__(256) void bn_kernel(const float* __restrict__ lamT,
                                                 const float* __restrict__ gamma,
                                                 const float* __restrict__ beta,
                                                 u16* __restrict__ bnT) {
    const int d = blockIdx.x;
    const int t = threadIdx.x;
    float vals[8];
    float s = 0.f, ss = 0.f;
#pragma unroll
    for (int i = 0; i < 8; ++i) {
        float v = lamT[(long)(i * 256 + t) * 256 + d];
        vals[i] = v;
        s += v;
        ss += v * v;
    }
#pragma unroll
    for (int sh = 32; sh > 0; sh >>= 1) {
        s += __shfl_xor(s, sh, 64);
        ss += __shfl_xor(ss, sh, 64);
    }
    __shared__ float red[8];
    int w = t >> 6;
    if ((t & 63) == 0) {
        red[w] = s;
        red[w + 4] = ss;
    }
    __syncthreads();
    s = red[0] + red[1] + red[2] + red[3];
    ss = red[4] + red[5] + red[6] + red[7];
    float mean = s * (1.f / 2048.f);
    float var = ss * (1.f / 2048.f) - mean * mean;
    float scale = gamma[d] * rsqrtf(var + 1e-5f);
    float shift = beta[d] - mean * scale;
#pragma unroll
    for (int i = 0; i < 8; ++i)
        bnT[(long)(i * 256 + t) * 256 + d] = f2b(vals[i] * scale + shift);
}

// ---------------------------------------------------------------------------
// outb[b][e] = sum_d bq[d] * bnT[b][e][d]   (folded query bias)
// ---------------------------------------------------------------------------
__global__ __launch_bounds__(256) void outb_kernel(const float* __restrict__ bq,
                                                   const u16* __restrict__ bnT,
                                                   float* __restrict__ outb) {
    int b = blockIdx.x, e = threadIdx.x;
    const u16* rowp = bnT + ((long)b * 256 + e) * 256;
    float s = 0.f;
    for (int dd = 0; dd < 256; ++dd) s += bq[dd] * b2f(rowp[dd]);
    outb[b * 256 + e] = s;
}

// ---------------------------------------------------------------------------
extern "C" void kernel_launch(void* const* d_in, const int* in_sizes, int n_in,
                              void* d_out, int out_size, void* d_ws, size_t ws_size,
                              hipStream_t stream) {
    const float* feat = (const float*)d_in[0];   // (8,8192,256) f32
    const float* W_qk = (const float*)d_in[1];   // (2,256,256) f32
    const float* b_qk = (const float*)d_in[2];   // (2,256) f32
    const float* W_v = (const float*)d_in[3];    // (256,256) f32
    const float* b_v = (const float*)d_in[4];    // (256,) f32
    const float* gamma = (const float*)d_in[5];  // (256,) f32
    const float* beta = (const float*)d_in[6];   // (256,) f32
    float* out = (float*)d_out;                  // (8,8192,256) f32

    char* ws = (char*)d_ws;
    u16* KT = (u16*)(ws);                        // [b][d][n] 32 MiB (P after softmax)
    u16* VT = (u16*)(ws + 33554432);             // [b][e][n] 32 MiB
    u16* WkT = (u16*)(ws + 67108864);            // 128 KiB
    u16* WvT = (u16*)(ws + 67239936);            // 128 KiB
    u16* Wqb = (u16*)(ws + 67371008);            // 128 KiB
    float* lamT = (float*)(ws + 67502080);       // 2 MiB -> ends 69,599,232
    u16* Xb = (ws_size >= 103153664u) ? (u16*)(ws + 69599232) : (u16*)0;  // 32 MiB bf16 X
    // lamP partials live in d_out (67 MB f32, dead until gemm_out32)
    float* lamPd = (float*)d_out;
    // post-splitk buffers alias the dead P region (KT):
    u16* bnT = (u16*)ws;                         // 1 MiB
    u16* WfoldT = (u16*)(ws + 2097152);          // 1 MiB
    float* outb = (float*)(ws + 4194304);        // 8 KiB

    // 1. weight prep
    prep_w<<<768, 256, 0, stream>>>(W_qk, W_v, WkT, WvT, Wqb);
    // 2. fused K^T / V^T projection + Xb side-write
    gemm_kvx<<<1024, 256, 0, stream>>>(feat, WkT, WvT, b_qk + 256, b_v, KT, VT, Xb);
    // 3. in-place softmax over n -> P^T
    softmax_rows<<<2048, 64, 0, stream>>>(KT);
    // 4. split-K lam partials (into d_out) + reduce
    gemm_splitk32<<<dim3(16, 2, 16), 256, 0, stream>>>(VT, KT, lamPd, 512);
    reduce_lam<<<512, 256, 0, stream>>>(lamPd, lamT, 16);
    // 5. BN -> bn^T bf16 (aliases dead P region)
    bn_kernel<<<256, 256, 0, stream>>>(lamT, gamma, beta, bnT);
    // 6. folded query bias
    outb_kernel<<<8, 256, 0, stream>>>(b_qk, bnT, outb);
    // 7. Wfold^T = bn^T @ Wq^T
    gemm_fold<<<dim3(32, 4), 256, 0, stream>>>(bnT, Wqb, WfoldT);
    // 8. out = X @ Wfold (+outb)
    gemm_out32<<<1024, 256, 0, stream>>>(feat, Xb, WfoldT, outb, out);
}